// Round 5
// baseline (208.271 us; speedup 1.0000x reference)
//
#include <hip/hip_runtime.h>
#include <math.h>

#define DD 768
#define NN 64
#define SS 512
#define BB 4
#define PF 4

__device__ __forceinline__ float sigmf(float v) { return 1.0f / (1.0f + expf(-v)); }

// ---- DPP add helper (bound_ctrl=0-fill) ----
template <int CTRL>
__device__ __forceinline__ float dppadd(float v) {
    int s = __builtin_amdgcn_update_dpp(0, __float_as_int(v), CTRL, 0xF, 0xF, true);
    return v + __int_as_float(s);
}
// sum within each 16-lane row; result valid in lane 15 of each row
__device__ __forceinline__ float row_sum15(float v) {
    v = dppadd<0x111>(v);  // row_shr:1
    v = dppadd<0x112>(v);  // row_shr:2
    v = dppadd<0x114>(v);  // row_shr:4
    v = dppadd<0x118>(v);  // row_shr:8
    return v;
}
// full 64-lane sum, valid in lane 63 (for fallback kernel)
__device__ __forceinline__ float wave_sum63(float v) {
    v = row_sum15(v);
    v = dppadd<0x142>(v);  // row_bcast:15
    v = dppadd<0x143>(v);  // row_bcast:31
    return v;
}

// ---- fused prep (blocks 0..11) + x-transpose (blocks 12..395) ----
// prep: BwT[d][n] = sigmoid(Braw[n][d]) via LDS tile; gamma_s = sigmoid(graw)
// xpose: x[b][t][d] -> xT[b][d][t], 64x64 tiles
__global__ __launch_bounds__(256) void prep_xpose_kernel(const float* __restrict__ Braw,
                                                         const float* __restrict__ graw,
                                                         const float* __restrict__ x,
                                                         float* __restrict__ BwT,
                                                         float* __restrict__ gamma_s,
                                                         float* __restrict__ xT) {
    __shared__ float tile[64][65];
    int tx = threadIdx.x & 63;
    int tq = threadIdx.x >> 6;  // 0..3
    if (blockIdx.x < 12) {
        int d0 = blockIdx.x * 64;
#pragma unroll
        for (int i = 0; i < 16; ++i) {
            int n = tq + i * 4;
            tile[n][tx] = sigmf(Braw[n * DD + d0 + tx]);  // coalesced over d
        }
        __syncthreads();
#pragma unroll
        for (int i = 0; i < 16; ++i) {
            int dl = tq + i * 4;
            BwT[(d0 + dl) * NN + tx] = tile[tx][dl];      // coalesced over n
        }
        int gi = blockIdx.x * 256 + threadIdx.x;
        if (gi < DD) gamma_s[gi] = sigmf(graw[gi]);
    } else {
        int bidx = blockIdx.x - 12;        // 0..383
        int b  = bidx / 96;
        int r  = bidx - b * 96;
        int t0 = (r / 12) * 64;
        int d0 = (r % 12) * 64;
#pragma unroll
        for (int i = 0; i < 16; ++i) {
            int t = tq + i * 4;
            tile[t][tx] = x[((size_t)b * SS + t0 + t) * DD + d0 + tx];
        }
        __syncthreads();
#pragma unroll
        for (int i = 0; i < 16; ++i) {
            int dl = tq + i * 4;
            xT[((size_t)b * DD + d0 + dl) * SS + t0 + tx] = tile[tx][dl];
        }
    }
}

// ---- phase 1: inp[r][n] = sum_d x[r][d] * BwT[d][n] ----
// Wave covers 4 rows (rl = lane>>4) x 16 n-quads (q = lane&15); each bw float4
// load is reused across the wave's 4 rows -> BwT traffic / 4.
__global__ __launch_bounds__(256) void inp_kernel(const float* __restrict__ x,
                                                  const float* __restrict__ BwT,
                                                  float* __restrict__ inp) {
    int wid  = (blockIdx.x * 256 + threadIdx.x) >> 6;  // 0..511
    int lane = threadIdx.x & 63;
    int rl = lane >> 4;   // row within wave
    int q  = lane & 15;   // n-quad
    int r  = wid * 4 + rl;
    const float4* xr4 = (const float4*)(x + (size_t)r * DD);
    const float4* bw4 = (const float4*)BwT + q;   // element d*16 + q

    // chunk = 8 d's: 8 bw float4 + 2 x float4 (broadcast within row group)
    float4 Aw0, Aw1, Aw2, Aw3, Aw4, Aw5, Aw6, Aw7, Ax0, Ax1;
    float4 Bw0, Bw1, Bw2, Bw3, Bw4, Bw5, Bw6, Bw7, Bx0, Bx1;
    float4 Cw0, Cw1, Cw2, Cw3, Cw4, Cw5, Cw6, Cw7, Cx0, Cx1;
    float4 Dw0, Dw1, Dw2, Dw3, Dw4, Dw5, Dw6, Dw7, Dx0, Dx1;

#define IPREF(P, C0)                                                 \
    {                                                                \
        int cc_ = ((C0) < 96) ? (C0) : 0;                            \
        P##w0 = bw4[(cc_ * 8 + 0) * 16];                             \
        P##w1 = bw4[(cc_ * 8 + 1) * 16];                             \
        P##w2 = bw4[(cc_ * 8 + 2) * 16];                             \
        P##w3 = bw4[(cc_ * 8 + 3) * 16];                             \
        P##w4 = bw4[(cc_ * 8 + 4) * 16];                             \
        P##w5 = bw4[(cc_ * 8 + 5) * 16];                             \
        P##w6 = bw4[(cc_ * 8 + 6) * 16];                             \
        P##w7 = bw4[(cc_ * 8 + 7) * 16];                             \
        P##x0 = xr4[cc_ * 2 + 0];                                    \
        P##x1 = xr4[cc_ * 2 + 1];                                    \
    }
#define IFMA(W, X)                       \
    acc.x = fmaf(X, W.x, acc.x);         \
    acc.y = fmaf(X, W.y, acc.y);         \
    acc.z = fmaf(X, W.z, acc.z);         \
    acc.w = fmaf(X, W.w, acc.w);
#define ICOMP(P)                                                     \
    IFMA(P##w0, P##x0.x) IFMA(P##w1, P##x0.y)                        \
    IFMA(P##w2, P##x0.z) IFMA(P##w3, P##x0.w)                        \
    IFMA(P##w4, P##x1.x) IFMA(P##w5, P##x1.y)                        \
    IFMA(P##w6, P##x1.z) IFMA(P##w7, P##x1.w)

    IPREF(A, 0) IPREF(B, 1) IPREF(C, 2) IPREF(D, 3)

    float4 acc = {0.f, 0.f, 0.f, 0.f};
    for (int c = 0; c < 96; c += 4) {
        ICOMP(A) IPREF(A, c + 4)
        ICOMP(B) IPREF(B, c + 5)
        ICOMP(C) IPREF(C, c + 6)
        ICOMP(D) IPREF(D, c + 7)
    }
    ((float4*)(inp + (size_t)r * NN))[q] = acc;
}

// ---- phase 2: scan. Wave = 4 d's x 64 n. lane: dl=lane>>4 (d), ng=lane&15.
// Each lane owns 4 n's (h,a,c float4). y-reduce = 4 fma + 4-dpp row sum.
__global__ __launch_bounds__(256) void scan_kernel(const float* __restrict__ xT,
                                                   const float* __restrict__ Araw,
                                                   const float* __restrict__ Craw,
                                                   const float* __restrict__ inp,
                                                   float* __restrict__ Y,
                                                   float* __restrict__ hfin) {
    int wid  = (blockIdx.x * 256 + threadIdx.x) >> 6;  // 0..767
    int lane = threadIdx.x & 63;
    int dl = lane >> 4;   // 0..3
    int ng = lane & 15;   // n-quad
    int b  = wid / 192;
    int d  = (wid - b * 192) * 4 + dl;

    float4 a4 = *((const float4*)(Araw + (size_t)d * NN) + ng);
    float4 c4 = *((const float4*)(Craw + (size_t)d * NN) + ng);
    a4.x = sigmf(a4.x); a4.y = sigmf(a4.y); a4.z = sigmf(a4.z); a4.w = sigmf(a4.w);
    c4.x = sigmf(c4.x); c4.y = sigmf(c4.y); c4.z = sigmf(c4.z); c4.w = sigmf(c4.w);

    const float4* ip4 = (const float4*)(inp + (size_t)(b * SS) * NN) + ng;  // [t*16]
    const float4* xt4 = (const float4*)(xT + ((size_t)b * DD + d) * SS);    // bcast in row
    float*        y_b = Y + (size_t)(b * SS) * DD + d;

    float4 Ai0, Ai1, Ai2, Ai3, Axv;
    float4 Bi0, Bi1, Bi2, Bi3, Bxv;
    float4 Ci0, Ci1, Ci2, Ci3, Cxv;
    float4 Di0, Di1, Di2, Di3, Dxv;
    float4 h = {0.f, 0.f, 0.f, 0.f};

#define SPREF(P, T0)                                                  \
    {                                                                 \
        int tt_ = ((T0) < SS) ? (T0) : 0;                             \
        P##i0 = ip4[(tt_ + 0) * 16];                                  \
        P##i1 = ip4[(tt_ + 1) * 16];                                  \
        P##i2 = ip4[(tt_ + 2) * 16];                                  \
        P##i3 = ip4[(tt_ + 3) * 16];                                  \
        P##xv = xt4[tt_ >> 2];                                        \
    }
#define SSTEP(IPV, XV, T)                                                        \
    {                                                                            \
        h.x = __builtin_amdgcn_fmed3f(fmaf(h.x, a4.x, IPV.x * (XV)), 0.f, 1.f);  \
        h.y = __builtin_amdgcn_fmed3f(fmaf(h.y, a4.y, IPV.y * (XV)), 0.f, 1.f);  \
        h.z = __builtin_amdgcn_fmed3f(fmaf(h.z, a4.z, IPV.z * (XV)), 0.f, 1.f);  \
        h.w = __builtin_amdgcn_fmed3f(fmaf(h.w, a4.w, IPV.w * (XV)), 0.f, 1.f);  \
        float ps_ = h.x * c4.x;                                                  \
        ps_ = fmaf(h.y, c4.y, ps_);                                              \
        ps_ = fmaf(h.z, c4.z, ps_);                                              \
        ps_ = fmaf(h.w, c4.w, ps_);                                              \
        ps_ = row_sum15(ps_);                                                    \
        if (ng == 15) y_b[(T) * DD] = ps_;                                       \
    }
#define SCOMP(P, T0)                    \
    SSTEP(P##i0, P##xv.x, (T0) + 0)     \
    SSTEP(P##i1, P##xv.y, (T0) + 1)     \
    SSTEP(P##i2, P##xv.z, (T0) + 2)     \
    SSTEP(P##i3, P##xv.w, (T0) + 3)

    SPREF(A, 0) SPREF(B, PF) SPREF(C, 2 * PF) SPREF(D, 3 * PF)

    for (int t0 = 0; t0 < SS; t0 += 4 * PF) {
        SCOMP(A, t0)          SPREF(A, t0 + 4 * PF)
        SCOMP(B, t0 + PF)     SPREF(B, t0 + 5 * PF)
        SCOMP(C, t0 + 2 * PF) SPREF(C, t0 + 6 * PF)
        SCOMP(D, t0 + 3 * PF) SPREF(D, t0 + 7 * PF)
    }
    ((float4*)(hfin + ((size_t)b * DD + d) * NN))[ng] = h;
}

// ---- fallback scan (no xT; strided x reads; old 1-n-per-lane mapping) ----
__global__ __launch_bounds__(256) void scan_fb_kernel(const float* __restrict__ x,
                                                      const float* __restrict__ Araw,
                                                      const float* __restrict__ Craw,
                                                      const float* __restrict__ inp,
                                                      float* __restrict__ Y,
                                                      float* __restrict__ hfin) {
    int wid  = (blockIdx.x * 256 + threadIdx.x) >> 6;
    int lane = threadIdx.x & 63;
    int b = wid / DD;
    int d = wid - b * DD;

    float a = sigmf(Araw[d * NN + lane]);
    float c = sigmf(Craw[d * NN + lane]);

    const float* ip_ptr = inp + (b * SS) * NN + lane;
    const float* x_ptr  = x   + (b * SS) * DD + d;
    float*       y_ptr  = Y   + (b * SS) * DD + d;

    float cip[8], cxv[8], nip[8], nxv[8];
#pragma unroll
    for (int i = 0; i < 8; ++i) {
        cip[i] = ip_ptr[i * NN];
        cxv[i] = x_ptr[i * DD];
    }
    float h = 0.f;
    for (int t0 = 0; t0 < SS; t0 += 8) {
        int tn = t0 + 8;
        if (tn >= SS) tn = SS - 8;
#pragma unroll
        for (int i = 0; i < 8; ++i) {
            nip[i] = ip_ptr[(tn + i) * NN];
            nxv[i] = x_ptr[(tn + i) * DD];
        }
#pragma unroll
        for (int i = 0; i < 8; ++i) {
            h = __builtin_amdgcn_fmed3f(fmaf(h, a, cip[i] * cxv[i]), 0.f, 1.f);
            float v = wave_sum63(h * c);
            if (lane == 63) y_ptr[(t0 + i) * DD] = v;
        }
#pragma unroll
        for (int i = 0; i < 8; ++i) { cip[i] = nip[i]; cxv[i] = nxv[i]; }
    }
    hfin[(size_t)wid * NN + lane] = h;
}

// ---- phase 3: in-place layernorm + gamma + residual + clip (float4) ----
__global__ __launch_bounds__(256) void ln_kernel(const float* __restrict__ x,
                                                 const float* __restrict__ gamma_s,
                                                 float* __restrict__ out) {
    int wid  = (blockIdx.x * 256 + threadIdx.x) >> 6;  // row 0..2047
    int lane = threadIdx.x & 63;
    float*       yr = out + (size_t)wid * DD;
    const float* xr = x   + (size_t)wid * DD;

    float4 y0 = ((const float4*)yr)[lane * 3 + 0];
    float4 y1 = ((const float4*)yr)[lane * 3 + 1];
    float4 y2 = ((const float4*)yr)[lane * 3 + 2];

    float s = ((y0.x + y0.y) + (y0.z + y0.w)) + ((y1.x + y1.y) + (y1.z + y1.w)) +
              ((y2.x + y2.y) + (y2.z + y2.w));
#pragma unroll
    for (int off = 32; off; off >>= 1) s += __shfl_xor(s, off, 64);
    float mu = s * (1.f / 768.f);

    float q = 0.f;
#define QACC(v)                 \
    {                           \
        float d0_ = (v) - mu;   \
        q = fmaf(d0_, d0_, q);  \
    }
    QACC(y0.x) QACC(y0.y) QACC(y0.z) QACC(y0.w)
    QACC(y1.x) QACC(y1.y) QACC(y1.z) QACC(y1.w)
    QACC(y2.x) QACC(y2.y) QACC(y2.z) QACC(y2.w)
#pragma unroll
    for (int off = 32; off; off >>= 1) q += __shfl_xor(q, off, 64);
    float inv = rsqrtf(q * (1.f / 768.f) + 1e-5f);

    float4 g0 = ((const float4*)gamma_s)[lane * 3 + 0];
    float4 g1 = ((const float4*)gamma_s)[lane * 3 + 1];
    float4 g2 = ((const float4*)gamma_s)[lane * 3 + 2];
    float4 x0 = ((const float4*)xr)[lane * 3 + 0];
    float4 x1 = ((const float4*)xr)[lane * 3 + 1];
    float4 x2 = ((const float4*)xr)[lane * 3 + 2];

#define FIN(yv, gv, xv) __builtin_amdgcn_fmed3f(fmaf((yv - mu) * inv, gv, xv), 0.f, 1.f)
    float4 o0, o1, o2;
    o0.x = FIN(y0.x, g0.x, x0.x); o0.y = FIN(y0.y, g0.y, x0.y);
    o0.z = FIN(y0.z, g0.z, x0.z); o0.w = FIN(y0.w, g0.w, x0.w);
    o1.x = FIN(y1.x, g1.x, x1.x); o1.y = FIN(y1.y, g1.y, x1.y);
    o1.z = FIN(y1.z, g1.z, x1.z); o1.w = FIN(y1.w, g1.w, x1.w);
    o2.x = FIN(y2.x, g2.x, x2.x); o2.y = FIN(y2.y, g2.y, x2.y);
    o2.z = FIN(y2.z, g2.z, x2.z); o2.w = FIN(y2.w, g2.w, x2.w);

    ((float4*)yr)[lane * 3 + 0] = o0;
    ((float4*)yr)[lane * 3 + 1] = o1;
    ((float4*)yr)[lane * 3 + 2] = o2;
}

extern "C" void kernel_launch(void* const* d_in, const int* in_sizes, int n_in,
                              void* d_out, int out_size, void* d_ws, size_t ws_size,
                              hipStream_t stream) {
    const float* x    = (const float*)d_in[0];  // [B,S,D]
    const float* Araw = (const float*)d_in[1];  // [D,N]
    const float* Braw = (const float*)d_in[2];  // [N,D]
    const float* Craw = (const float*)d_in[3];  // [D,N]
    const float* graw = (const float*)d_in[4];  // [D]

    float* out  = (float*)d_out;                // [B,S,D] then [B,D,N]
    float* hfin = out + (size_t)BB * SS * DD;

    float* ws      = (float*)d_ws;
    float* BwT     = ws;                                   // D*N   = 49152
    float* gamma_s = ws + DD * NN;                         // D     = 768
    float* inp     = ws + DD * NN + DD;                    // B*S*N = 131072
    float* xT      = ws + DD * NN + DD + BB * SS * NN;     // B*D*S = 1572864

    size_t need = (size_t)(DD * NN + DD + (size_t)BB * SS * NN + (size_t)BB * SS * DD) * sizeof(float);

    if (ws_size >= need) {
        prep_xpose_kernel<<<12 + BB * (SS / 64) * (DD / 64), 256, 0, stream>>>(
            Braw, graw, x, BwT, gamma_s, xT);
        inp_kernel<<<(BB * SS) / 4 * 64 / 256, 256, 0, stream>>>(x, BwT, inp);
        scan_kernel<<<(BB * DD / 4) * 64 / 256, 256, 0, stream>>>(xT, Araw, Craw, inp, out, hfin);
    } else {
        prep_xpose_kernel<<<12, 256, 0, stream>>>(Braw, graw, x, BwT, gamma_s, xT);
        inp_kernel<<<(BB * SS) / 4 * 64 / 256, 256, 0, stream>>>(x, BwT, inp);
        scan_fb_kernel<<<(BB * DD * NN) / 256, 256, 0, stream>>>(x, Araw, Craw, inp, out, hfin);
    }
    ln_kernel<<<(BB * SS * NN) / 256, 256, 0, stream>>>(x, gamma_s, out);
}

// Round 6
// 98.485 us; speedup vs baseline: 2.1147x; 2.1147x over previous
//
#include <hip/hip_runtime.h>
#include <math.h>

#define DD 768
#define NN 64
#define SS 512
#define BB 4
#define PF 4

__device__ __forceinline__ float sigmf(float v) { return 1.0f / (1.0f + expf(-v)); }

// ---- DPP add helper (bound_ctrl=0-fill) ----
template <int CTRL>
__device__ __forceinline__ float dppadd(float v) {
    int s = __builtin_amdgcn_update_dpp(0, __float_as_int(v), CTRL, 0xF, 0xF, true);
    return v + __int_as_float(s);
}
// sum within each 16-lane row; result valid in lane 15 of each row
__device__ __forceinline__ float row_sum15(float v) {
    v = dppadd<0x111>(v);  // row_shr:1
    v = dppadd<0x112>(v);  // row_shr:2
    v = dppadd<0x114>(v);  // row_shr:4
    v = dppadd<0x118>(v);  // row_shr:8
    return v;
}
// full 64-lane sum, valid in lane 63 (for fallback kernel)
__device__ __forceinline__ float wave_sum63(float v) {
    v = row_sum15(v);
    v = dppadd<0x142>(v);  // row_bcast:15
    v = dppadd<0x143>(v);  // row_bcast:31
    return v;
}

// ---- fused prep (blocks 0..11) + x-transpose (blocks 12..395) ----
__global__ __launch_bounds__(256) void prep_xpose_kernel(const float* __restrict__ Braw,
                                                         const float* __restrict__ graw,
                                                         const float* __restrict__ x,
                                                         float* __restrict__ BwT,
                                                         float* __restrict__ gamma_s,
                                                         float* __restrict__ xT) {
    __shared__ float tile[64][65];
    int tx = threadIdx.x & 63;
    int tq = threadIdx.x >> 6;  // 0..3
    if (blockIdx.x < 12) {
        int d0 = blockIdx.x * 64;
#pragma unroll
        for (int i = 0; i < 16; ++i) {
            int n = tq + i * 4;
            tile[n][tx] = sigmf(Braw[n * DD + d0 + tx]);  // coalesced over d
        }
        __syncthreads();
#pragma unroll
        for (int i = 0; i < 16; ++i) {
            int dl = tq + i * 4;
            BwT[(d0 + dl) * NN + tx] = tile[tx][dl];      // coalesced over n
        }
        int gi = blockIdx.x * 256 + threadIdx.x;
        if (gi < DD) gamma_s[gi] = sigmf(graw[gi]);
    } else {
        int bidx = blockIdx.x - 12;        // 0..383
        int b  = bidx / 96;
        int r  = bidx - b * 96;
        int t0 = (r / 12) * 64;
        int d0 = (r % 12) * 64;
#pragma unroll
        for (int i = 0; i < 16; ++i) {
            int t = tq + i * 4;
            tile[t][tx] = x[((size_t)b * SS + t0 + t) * DD + d0 + tx];
        }
        __syncthreads();
#pragma unroll
        for (int i = 0; i < 16; ++i) {
            int dl = tq + i * 4;
            xT[((size_t)b * DD + d0 + dl) * SS + t0 + tx] = tile[tx][dl];
        }
    }
}

// ---- phase 1 (R4-proven): inp[r][n] = sum_d x[r][d] * BwT[d][n] ----
// Wave = row r. lane: g = lane>>4 (d-subgroup), q = lane&15 (n-quad).
// bw loads: 1KB/wave contiguous; x loads: 16B broadcast. 4-buffer rotation.
__global__ __launch_bounds__(256) void inp_kernel(const float* __restrict__ x,
                                                  const float* __restrict__ BwT,
                                                  float* __restrict__ inp) {
    int wid  = (blockIdx.x * 256 + threadIdx.x) >> 6;  // row 0..2047
    int lane = threadIdx.x & 63;
    int g = lane >> 4;
    int q = lane & 15;
    const float*  xr  = x + (size_t)wid * DD;
    const float4* bw4 = (const float4*)BwT + q;        // element d*16 + q

    float4 Aw0, Aw1, Aw2, Aw3; float Ax0, Ax1, Ax2, Ax3;
    float4 Bw0, Bw1, Bw2, Bw3; float Bx0, Bx1, Bx2, Bx3;
    float4 Cw0, Cw1, Cw2, Cw3; float Cx0, Cx1, Cx2, Cx3;
    float4 Dw0, Dw1, Dw2, Dw3; float Dx0, Dx1, Dx2, Dx3;

    // group c covers d = 16c .. 16c+15; j-th slot: d = 16c + 4j + g
#define IPREF(P, C0)                                                     \
    {                                                                    \
        int cc_ = ((C0) < 48) ? (C0) : 0;                                \
        P##w0 = bw4[(16 * cc_ + 0 + g) * 16];                            \
        P##w1 = bw4[(16 * cc_ + 4 + g) * 16];                            \
        P##w2 = bw4[(16 * cc_ + 8 + g) * 16];                            \
        P##w3 = bw4[(16 * cc_ + 12 + g) * 16];                           \
        P##x0 = xr[16 * cc_ + 0 + g];                                    \
        P##x1 = xr[16 * cc_ + 4 + g];                                    \
        P##x2 = xr[16 * cc_ + 8 + g];                                    \
        P##x3 = xr[16 * cc_ + 12 + g];                                   \
    }
#define IFMA(W, X)                       \
    acc.x = fmaf(X, W.x, acc.x);         \
    acc.y = fmaf(X, W.y, acc.y);         \
    acc.z = fmaf(X, W.z, acc.z);         \
    acc.w = fmaf(X, W.w, acc.w);
#define ICOMP(P)                         \
    IFMA(P##w0, P##x0) IFMA(P##w1, P##x1) IFMA(P##w2, P##x2) IFMA(P##w3, P##x3)

    IPREF(A, 0) IPREF(B, 1) IPREF(C, 2) IPREF(D, 3)

    float4 acc = {0.f, 0.f, 0.f, 0.f};
    for (int c = 0; c < 48; c += 4) {
        ICOMP(A) IPREF(A, c + 4)
        ICOMP(B) IPREF(B, c + 5)
        ICOMP(C) IPREF(C, c + 6)
        ICOMP(D) IPREF(D, c + 7)
    }

    // combine the 4 d-subgroups: lanes l, l^16, l^32
#pragma unroll
    for (int off = 16; off <= 32; off <<= 1) {
        acc.x += __shfl_xor(acc.x, off, 64);
        acc.y += __shfl_xor(acc.y, off, 64);
        acc.z += __shfl_xor(acc.z, off, 64);
        acc.w += __shfl_xor(acc.w, off, 64);
    }
    if (lane < 16) ((float4*)(inp + (size_t)wid * NN))[q] = acc;
}

// ---- phase 2: scan. Wave = 4 d's x 64 n. lane: dl=lane>>4 (d), ng=lane&15.
// Each lane owns 4 n's (h,a,c float4). y-reduce = 4 fma + 4-dpp row sum.
__global__ __launch_bounds__(256) void scan_kernel(const float* __restrict__ xT,
                                                   const float* __restrict__ Araw,
                                                   const float* __restrict__ Craw,
                                                   const float* __restrict__ inp,
                                                   float* __restrict__ Y,
                                                   float* __restrict__ hfin) {
    int wid  = (blockIdx.x * 256 + threadIdx.x) >> 6;  // 0..767
    int lane = threadIdx.x & 63;
    int dl = lane >> 4;   // 0..3
    int ng = lane & 15;   // n-quad
    int b  = wid / 192;
    int d  = (wid - b * 192) * 4 + dl;

    float4 a4 = *((const float4*)(Araw + (size_t)d * NN) + ng);
    float4 c4 = *((const float4*)(Craw + (size_t)d * NN) + ng);
    a4.x = sigmf(a4.x); a4.y = sigmf(a4.y); a4.z = sigmf(a4.z); a4.w = sigmf(a4.w);
    c4.x = sigmf(c4.x); c4.y = sigmf(c4.y); c4.z = sigmf(c4.z); c4.w = sigmf(c4.w);

    const float4* ip4 = (const float4*)(inp + (size_t)(b * SS) * NN) + ng;  // [t*16]
    const float4* xt4 = (const float4*)(xT + ((size_t)b * DD + d) * SS);    // bcast in row
    float*        y_b = Y + (size_t)(b * SS) * DD + d;

    float4 Ai0, Ai1, Ai2, Ai3, Axv;
    float4 Bi0, Bi1, Bi2, Bi3, Bxv;
    float4 Ci0, Ci1, Ci2, Ci3, Cxv;
    float4 Di0, Di1, Di2, Di3, Dxv;
    float4 h = {0.f, 0.f, 0.f, 0.f};

#define SPREF(P, T0)                                                  \
    {                                                                 \
        int tt_ = ((T0) < SS) ? (T0) : 0;                             \
        P##i0 = ip4[(tt_ + 0) * 16];                                  \
        P##i1 = ip4[(tt_ + 1) * 16];                                  \
        P##i2 = ip4[(tt_ + 2) * 16];                                  \
        P##i3 = ip4[(tt_ + 3) * 16];                                  \
        P##xv = xt4[tt_ >> 2];                                        \
    }
#define SSTEP(IPV, XV, T)                                                        \
    {                                                                            \
        h.x = __builtin_amdgcn_fmed3f(fmaf(h.x, a4.x, IPV.x * (XV)), 0.f, 1.f);  \
        h.y = __builtin_amdgcn_fmed3f(fmaf(h.y, a4.y, IPV.y * (XV)), 0.f, 1.f);  \
        h.z = __builtin_amdgcn_fmed3f(fmaf(h.z, a4.z, IPV.z * (XV)), 0.f, 1.f);  \
        h.w = __builtin_amdgcn_fmed3f(fmaf(h.w, a4.w, IPV.w * (XV)), 0.f, 1.f);  \
        float ps_ = h.x * c4.x;                                                  \
        ps_ = fmaf(h.y, c4.y, ps_);                                              \
        ps_ = fmaf(h.z, c4.z, ps_);                                              \
        ps_ = fmaf(h.w, c4.w, ps_);                                              \
        ps_ = row_sum15(ps_);                                                    \
        if (ng == 15) y_b[(T) * DD] = ps_;                                       \
    }
#define SCOMP(P, T0)                    \
    SSTEP(P##i0, P##xv.x, (T0) + 0)     \
    SSTEP(P##i1, P##xv.y, (T0) + 1)     \
    SSTEP(P##i2, P##xv.z, (T0) + 2)     \
    SSTEP(P##i3, P##xv.w, (T0) + 3)

    SPREF(A, 0) SPREF(B, PF) SPREF(C, 2 * PF) SPREF(D, 3 * PF)

    for (int t0 = 0; t0 < SS; t0 += 4 * PF) {
        SCOMP(A, t0)          SPREF(A, t0 + 4 * PF)
        SCOMP(B, t0 + PF)     SPREF(B, t0 + 5 * PF)
        SCOMP(C, t0 + 2 * PF) SPREF(C, t0 + 6 * PF)
        SCOMP(D, t0 + 3 * PF) SPREF(D, t0 + 7 * PF)
    }
    ((float4*)(hfin + ((size_t)b * DD + d) * NN))[ng] = h;
}

// ---- fallback scan (no xT; strided x reads; 1-n-per-lane mapping) ----
__global__ __launch_bounds__(256) void scan_fb_kernel(const float* __restrict__ x,
                                                      const float* __restrict__ Araw,
                                                      const float* __restrict__ Craw,
                                                      const float* __restrict__ inp,
                                                      float* __restrict__ Y,
                                                      float* __restrict__ hfin) {
    int wid  = (blockIdx.x * 256 + threadIdx.x) >> 6;
    int lane = threadIdx.x & 63;
    int b = wid / DD;
    int d = wid - b * DD;

    float a = sigmf(Araw[d * NN + lane]);
    float c = sigmf(Craw[d * NN + lane]);

    const float* ip_ptr = inp + (b * SS) * NN + lane;
    const float* x_ptr  = x   + (b * SS) * DD + d;
    float*       y_ptr  = Y   + (b * SS) * DD + d;

    float cip[8], cxv[8], nip[8], nxv[8];
#pragma unroll
    for (int i = 0; i < 8; ++i) {
        cip[i] = ip_ptr[i * NN];
        cxv[i] = x_ptr[i * DD];
    }
    float h = 0.f;
    for (int t0 = 0; t0 < SS; t0 += 8) {
        int tn = t0 + 8;
        if (tn >= SS) tn = SS - 8;
#pragma unroll
        for (int i = 0; i < 8; ++i) {
            nip[i] = ip_ptr[(tn + i) * NN];
            nxv[i] = x_ptr[(tn + i) * DD];
        }
#pragma unroll
        for (int i = 0; i < 8; ++i) {
            h = __builtin_amdgcn_fmed3f(fmaf(h, a, cip[i] * cxv[i]), 0.f, 1.f);
            float v = wave_sum63(h * c);
            if (lane == 63) y_ptr[(t0 + i) * DD] = v;
        }
#pragma unroll
        for (int i = 0; i < 8; ++i) { cip[i] = nip[i]; cxv[i] = nxv[i]; }
    }
    hfin[(size_t)wid * NN + lane] = h;
}

// ---- phase 3: in-place layernorm + gamma + residual + clip (float4) ----
__global__ __launch_bounds__(256) void ln_kernel(const float* __restrict__ x,
                                                 const float* __restrict__ gamma_s,
                                                 float* __restrict__ out) {
    int wid  = (blockIdx.x * 256 + threadIdx.x) >> 6;  // row 0..2047
    int lane = threadIdx.x & 63;
    float*       yr = out + (size_t)wid * DD;
    const float* xr = x   + (size_t)wid * DD;

    float4 y0 = ((const float4*)yr)[lane * 3 + 0];
    float4 y1 = ((const float4*)yr)[lane * 3 + 1];
    float4 y2 = ((const float4*)yr)[lane * 3 + 2];

    float s = ((y0.x + y0.y) + (y0.z + y0.w)) + ((y1.x + y1.y) + (y1.z + y1.w)) +
              ((y2.x + y2.y) + (y2.z + y2.w));
#pragma unroll
    for (int off = 32; off; off >>= 1) s += __shfl_xor(s, off, 64);
    float mu = s * (1.f / 768.f);

    float q = 0.f;
#define QACC(v)                 \
    {                           \
        float d0_ = (v) - mu;   \
        q = fmaf(d0_, d0_, q);  \
    }
    QACC(y0.x) QACC(y0.y) QACC(y0.z) QACC(y0.w)
    QACC(y1.x) QACC(y1.y) QACC(y1.z) QACC(y1.w)
    QACC(y2.x) QACC(y2.y) QACC(y2.z) QACC(y2.w)
#pragma unroll
    for (int off = 32; off; off >>= 1) q += __shfl_xor(q, off, 64);
    float inv = rsqrtf(q * (1.f / 768.f) + 1e-5f);

    float4 g0 = ((const float4*)gamma_s)[lane * 3 + 0];
    float4 g1 = ((const float4*)gamma_s)[lane * 3 + 1];
    float4 g2 = ((const float4*)gamma_s)[lane * 3 + 2];
    float4 x0 = ((const float4*)xr)[lane * 3 + 0];
    float4 x1 = ((const float4*)xr)[lane * 3 + 1];
    float4 x2 = ((const float4*)xr)[lane * 3 + 2];

#define FIN(yv, gv, xv) __builtin_amdgcn_fmed3f(fmaf((yv - mu) * inv, gv, xv), 0.f, 1.f)
    float4 o0, o1, o2;
    o0.x = FIN(y0.x, g0.x, x0.x); o0.y = FIN(y0.y, g0.y, x0.y);
    o0.z = FIN(y0.z, g0.z, x0.z); o0.w = FIN(y0.w, g0.w, x0.w);
    o1.x = FIN(y1.x, g1.x, x1.x); o1.y = FIN(y1.y, g1.y, x1.y);
    o1.z = FIN(y1.z, g1.z, x1.z); o1.w = FIN(y1.w, g1.w, x1.w);
    o2.x = FIN(y2.x, g2.x, x2.x); o2.y = FIN(y2.y, g2.y, x2.y);
    o2.z = FIN(y2.z, g2.z, x2.z); o2.w = FIN(y2.w, g2.w, x2.w);

    ((float4*)yr)[lane * 3 + 0] = o0;
    ((float4*)yr)[lane * 3 + 1] = o1;
    ((float4*)yr)[lane * 3 + 2] = o2;
}

extern "C" void kernel_launch(void* const* d_in, const int* in_sizes, int n_in,
                              void* d_out, int out_size, void* d_ws, size_t ws_size,
                              hipStream_t stream) {
    const float* x    = (const float*)d_in[0];  // [B,S,D]
    const float* Araw = (const float*)d_in[1];  // [D,N]
    const float* Braw = (const float*)d_in[2];  // [N,D]
    const float* Craw = (const float*)d_in[3];  // [D,N]
    const float* graw = (const float*)d_in[4];  // [D]

    float* out  = (float*)d_out;                // [B,S,D] then [B,D,N]
    float* hfin = out + (size_t)BB * SS * DD;

    float* ws      = (float*)d_ws;
    float* BwT     = ws;                                   // D*N   = 49152
    float* gamma_s = ws + DD * NN;                         // D     = 768
    float* inp     = ws + DD * NN + DD;                    // B*S*N = 131072
    float* xT      = ws + DD * NN + DD + BB * SS * NN;     // B*D*S = 1572864

    size_t need = (size_t)(DD * NN + DD + (size_t)BB * SS * NN + (size_t)BB * SS * DD) * sizeof(float);

    if (ws_size >= need) {
        prep_xpose_kernel<<<12 + BB * (SS / 64) * (DD / 64), 256, 0, stream>>>(
            Braw, graw, x, BwT, gamma_s, xT);
        inp_kernel<<<(BB * SS * NN) / 256, 256, 0, stream>>>(x, BwT, inp);
        scan_kernel<<<(BB * DD / 4) * 64 / 256, 256, 0, stream>>>(xT, Araw, Craw, inp, out, hfin);
    } else {
        prep_xpose_kernel<<<12, 256, 0, stream>>>(Braw, graw, x, BwT, gamma_s, xT);
        inp_kernel<<<(BB * SS * NN) / 256, 256, 0, stream>>>(x, BwT, inp);
        scan_fb_kernel<<<(BB * DD * NN) / 256, 256, 0, stream>>>(x, Araw, Craw, inp, out, hfin);
    }
    ln_kernel<<<(BB * SS * NN) / 256, 256, 0, stream>>>(x, gamma_s, out);
}